// Round 3
// baseline (687.543 us; speedup 1.0000x reference)
//
#include <hip/hip_runtime.h>
#include <hip/hip_bf16.h>
#include <math.h>

// N=100000 nodes, E=600000 edges, F=H=128, B=250 graphs, 400 nodes/graph.
//
// Pipeline:
//   CSR build (histogram -> scan -> fill), dinv, cluster
//   3x { agg: tmp = (D^-1/2 (A+I) D^-1/2) h   -- gathers from a bf16 copy of h
//        gemm: h' = relu(tmp @ W + b)         -- fp32 math; also emits bf16 copy }
//   pool_part (16 partials/graph) + head
//
// R1: pool 113us @5% occupancy -> split into 16 partials/graph. 671->572us.
// R2: agg dominated (3x87us, FETCH 177MB, gather-byte bound). Gather h in bf16:
//     256B/row = 64 lanes x 1 uint, fp32 accumulate. Predicted agg ~50us each.

#define WAVE 64
#define NPARTS 16

__device__ __forceinline__ float bflo(unsigned u) {
    return __uint_as_float(u << 16);
}
__device__ __forceinline__ float bfhi(unsigned u) {
    return __uint_as_float(u & 0xffff0000u);
}
__device__ __forceinline__ unsigned pack_bf16(float a, float b) {
    unsigned ua = __float_as_uint(a), ub = __float_as_uint(b);
    ua = (ua + 0x7fffu + ((ua >> 16) & 1u)) >> 16;
    ub = (ub + 0x7fffu + ((ub >> 16) & 1u)) >> 16;
    return ua | (ub << 16);
}

// ---------------- CSR build ----------------

__global__ void count_kernel(const int* __restrict__ dst, int* __restrict__ cnt, int ne) {
    int e = blockIdx.x * blockDim.x + threadIdx.x;
    if (e < ne) atomicAdd(&cnt[dst[e]], 1);
}

__global__ void dinv_kernel(const int* __restrict__ cnt, const float* __restrict__ x,
                            float* __restrict__ dinv, int* __restrict__ cluster, int n) {
    int i = blockIdx.x * blockDim.x + threadIdx.x;
    if (i >= n) return;
    dinv[i] = rsqrtf((float)(cnt[i] + 1));
    float c = x[(size_t)i * 128 + 127] + 2.0f * x[(size_t)i * 128 + 126];
    cluster[i] = (int)(c + 0.5f);
}

// fp32 -> bf16 conversion: each thread converts 4 floats -> 2 uints
__global__ void f2bf_kernel(const float* __restrict__ in, unsigned* __restrict__ out,
                            int n4) {
    int i = blockIdx.x * blockDim.x + threadIdx.x;
    if (i >= n4) return;
    float4 v = ((const float4*)in)[i];
    out[i * 2 + 0] = pack_bf16(v.x, v.y);
    out[i * 2 + 1] = pack_bf16(v.z, v.w);
}

// exclusive scan of cnt -> row_ptr, 1024 elements per block
__global__ void scan_block(const int* __restrict__ in, int* __restrict__ out,
                           int* __restrict__ bsums, int n) {
    __shared__ int lds[256];
    int t = threadIdx.x;
    int base = blockIdx.x * 1024 + t * 4;
    int v0 = (base + 0 < n) ? in[base + 0] : 0;
    int v1 = (base + 1 < n) ? in[base + 1] : 0;
    int v2 = (base + 2 < n) ? in[base + 2] : 0;
    int v3 = (base + 3 < n) ? in[base + 3] : 0;
    int s = v0 + v1 + v2 + v3;
    lds[t] = s;
    __syncthreads();
    for (int off = 1; off < 256; off <<= 1) {
        int add = (t >= off) ? lds[t - off] : 0;
        __syncthreads();
        lds[t] += add;
        __syncthreads();
    }
    int excl = lds[t] - s;
    if (base + 0 < n) out[base + 0] = excl;
    if (base + 1 < n) out[base + 1] = excl + v0;
    if (base + 2 < n) out[base + 2] = excl + v0 + v1;
    if (base + 3 < n) out[base + 3] = excl + v0 + v1 + v2;
    if (t == 255) bsums[blockIdx.x] = lds[255];
}

__global__ void scan_bsums(int* __restrict__ bsums, int nb) {
    __shared__ int lds[256];
    int t = threadIdx.x;
    int v = (t < nb) ? bsums[t] : 0;
    lds[t] = v;
    __syncthreads();
    for (int off = 1; off < 256; off <<= 1) {
        int add = (t >= off) ? lds[t - off] : 0;
        __syncthreads();
        lds[t] += add;
        __syncthreads();
    }
    if (t < nb) bsums[t] = lds[t] - v;   // exclusive
}

__global__ void scan_add(int* __restrict__ out, const int* __restrict__ bsums, int n) {
    int base = blockIdx.x * 1024 + threadIdx.x * 4;
    int add = bsums[blockIdx.x];
#pragma unroll
    for (int i = 0; i < 4; ++i)
        if (base + i < n) out[base + i] += add;
}

__global__ void fill_kernel(const int* __restrict__ src, const int* __restrict__ dst,
                            const int* __restrict__ row_ptr, int* __restrict__ fill,
                            int* __restrict__ col, int ne) {
    int e = blockIdx.x * blockDim.x + threadIdx.x;
    if (e < ne) {
        int d = dst[e];
        int pos = row_ptr[d] + atomicAdd(&fill[d], 1);
        col[pos] = src[e];
    }
}

// ---------------- normalized aggregation: one wave per node, bf16 gathers ----------
// out[n][:] = dinv[n]^2 * hb[n][:] + sum_{s in N_in(n)} dinv[n]*dinv[s]*hb[s][:]
// hb is the bf16 copy of h: row = 64 uints, lane loads uint = features (2l, 2l+1).

__global__ void agg_kernel(const unsigned* __restrict__ hb, float* __restrict__ out,
                           const int* __restrict__ row_ptr, const int* __restrict__ cnt,
                           const int* __restrict__ col, const float* __restrict__ dinv,
                           int n) {
    int node = blockIdx.x * (blockDim.x / WAVE) + (threadIdx.x >> 6);
    if (node >= n) return;
    int lane = threadIdx.x & 63;
    float di = dinv[node];
    unsigned self = hb[(size_t)node * 64 + lane];
    float w0 = di * di;
    float ax = bflo(self) * w0;
    float ay = bfhi(self) * w0;
    int s0 = row_ptr[node];
    int d  = cnt[node];
    int i = 0;
    for (; i + 1 < d; i += 2) {              // 2-way unroll for MLP
        int sa = col[s0 + i];
        int sb = col[s0 + i + 1];
        float wa = di * dinv[sa];
        float wb = di * dinv[sb];
        unsigned ua = hb[(size_t)sa * 64 + lane];
        unsigned ub = hb[(size_t)sb * 64 + lane];
        ax += wa * bflo(ua) + wb * bflo(ub);
        ay += wa * bfhi(ua) + wb * bfhi(ub);
    }
    if (i < d) {
        int s = col[s0 + i];
        float w = di * dinv[s];
        unsigned u = hb[(size_t)s * 64 + lane];
        ax += w * bflo(u);
        ay += w * bfhi(u);
    }
    float2 acc = make_float2(ax, ay);
    ((float2*)out)[(size_t)node * 64 + lane] = acc;
}

// ---------------- fp32 GEMM: C[M][128] = A[M][128] @ W[128][128] (+bias, relu) ----------
// Also emits bf16 copy of C into Cb when Cb != nullptr (for next layer's gathers).

__global__ __launch_bounds__(256) void gemm128(const float* __restrict__ A,
                                               const float* __restrict__ W,
                                               const float* __restrict__ bias,
                                               float* __restrict__ C,
                                               unsigned* __restrict__ Cb, int relu) {
    __shared__ float sA[64 * 132];
    __shared__ float sW[64 * 64];
    const int t  = threadIdx.x;
    const int m0 = blockIdx.x * 64;
    const int c0 = blockIdx.y * 64;

#pragma unroll
    for (int i = 0; i < 8; ++i) {
        int idx = t * 4 + i * 1024;
        int r = idx >> 7, c = idx & 127;
        *(float4*)&sA[r * 132 + c] = *(const float4*)&A[(size_t)(m0 + r) * 128 + c];
    }

    const int tx = t & 15, ty = t >> 4;
    const int r0 = ty * 4, cc = tx * 4;
    float acc[4][4];
#pragma unroll
    for (int i = 0; i < 4; ++i)
#pragma unroll
        for (int j = 0; j < 4; ++j) acc[i][j] = 0.0f;

    for (int kh = 0; kh < 2; ++kh) {
        __syncthreads();
#pragma unroll
        for (int i = 0; i < 4; ++i) {
            int idx = t * 4 + i * 1024;
            int k = idx >> 6, c = idx & 63;
            *(float4*)&sW[k * 64 + c] =
                *(const float4*)&W[(size_t)(kh * 64 + k) * 128 + c0 + c];
        }
        __syncthreads();

        const int kbase = kh * 64;
        for (int k = 0; k < 64; k += 4) {
            float aa[4][4], ww[4][4];
#pragma unroll
            for (int i = 0; i < 4; ++i) {
                float4 v = *(const float4*)&sA[(r0 + i) * 132 + kbase + k];
                aa[i][0] = v.x; aa[i][1] = v.y; aa[i][2] = v.z; aa[i][3] = v.w;
            }
#pragma unroll
            for (int kk = 0; kk < 4; ++kk) {
                float4 v = *(const float4*)&sW[(k + kk) * 64 + cc];
                ww[kk][0] = v.x; ww[kk][1] = v.y; ww[kk][2] = v.z; ww[kk][3] = v.w;
            }
#pragma unroll
            for (int i = 0; i < 4; ++i)
#pragma unroll
                for (int j = 0; j < 4; ++j)
#pragma unroll
                    for (int kk = 0; kk < 4; ++kk)
                        acc[i][j] += aa[i][kk] * ww[kk][j];
        }
    }

    float4 b4 = *(const float4*)&bias[c0 + cc];
#pragma unroll
    for (int i = 0; i < 4; ++i) {
        float4 o;
        o.x = acc[i][0] + b4.x;
        o.y = acc[i][1] + b4.y;
        o.z = acc[i][2] + b4.z;
        o.w = acc[i][3] + b4.w;
        if (relu) {
            o.x = fmaxf(o.x, 0.0f); o.y = fmaxf(o.y, 0.0f);
            o.z = fmaxf(o.z, 0.0f); o.w = fmaxf(o.w, 0.0f);
        }
        size_t row = (size_t)(m0 + r0 + i);
        *(float4*)&C[row * 128 + c0 + cc] = o;
        if (Cb) {
            uint2 p;
            p.x = pack_bf16(o.x, o.y);
            p.y = pack_bf16(o.z, o.w);
            *(uint2*)&Cb[row * 64 + (c0 + cc) / 2] = p;
        }
    }
}

// ---------------- pooling: 16 partial blocks per graph ----------------

__global__ void pool_part(const float* __restrict__ h, const int* __restrict__ cluster,
                          float* __restrict__ part_sums, int* __restrict__ part_cnts,
                          int npg) {
    int blk = blockIdx.x;
    int g = blk / NPARTS, p = blk % NPARTS;
    int j = threadIdx.x;
    int per = npg / NPARTS;
    int base = g * npg + p * per;
    float a0 = 0.f, a1 = 0.f, a2 = 0.f;
    int n0 = 0, n1 = 0, n2 = 0;
    for (int i = 0; i < per; ++i) {
        int node = base + i;
        float v = h[(size_t)node * 128 + j];
        int c = cluster[node];
        if (c == 0)      { a0 += v; n0++; }
        else if (c == 1) { a1 += v; n1++; }
        else             { a2 += v; n2++; }
    }
    size_t o = (size_t)blk * 3 * 128 + j;
    part_sums[o]       = a0;
    part_sums[o + 128] = a1;
    part_sums[o + 256] = a2;
    if (j == 0) {
        part_cnts[blk * 3 + 0] = n0;
        part_cnts[blk * 3 + 1] = n1;
        part_cnts[blk * 3 + 2] = n2;
    }
}

__global__ void head_kernel(const float* __restrict__ part_sums,
                            const int* __restrict__ part_cnts,
                            const float* __restrict__ Wl, const float* __restrict__ bl,
                            float* __restrict__ out) {
    int b = blockIdx.x, t = threadIdx.x;
    float s0 = 0.f, s1 = 0.f, s2 = 0.f;
    int n0 = 0, n1 = 0, n2 = 0;
#pragma unroll
    for (int p = 0; p < NPARTS; ++p) {
        int blk = b * NPARTS + p;
        size_t o = (size_t)blk * 3 * 128 + t;
        s0 += part_sums[o];
        s1 += part_sums[o + 128];
        s2 += part_sums[o + 256];
        n0 += part_cnts[blk * 3 + 0];
        n1 += part_cnts[blk * 3 + 1];
        n2 += part_cnts[blk * 3 + 2];
    }
    float z = s0 * (1.0f / fmaxf((float)n0, 1.0f)) * Wl[t]
            + s1 * (1.0f / fmaxf((float)n1, 1.0f)) * Wl[128 + t]
            + s2 * (1.0f / fmaxf((float)n2, 1.0f)) * Wl[256 + t];
    for (int off = 32; off > 0; off >>= 1) z += __shfl_down(z, off);
    __shared__ float partial[2];
    if ((t & 63) == 0) partial[t >> 6] = z;
    __syncthreads();
    if (t == 0) {
        float zz = partial[0] + partial[1] + bl[0];
        out[b] = 1.0f / (1.0f + expf(-zz));
    }
}

// ---------------- host ----------------

extern "C" void kernel_launch(void* const* d_in, const int* in_sizes, int n_in,
                              void* d_out, int out_size, void* d_ws, size_t ws_size,
                              hipStream_t stream) {
    const float* x     = (const float*)d_in[0];
    const int*   ei    = (const int*)d_in[1];
    const float* W1 = (const float*)d_in[3];
    const float* b1 = (const float*)d_in[4];
    const float* W2 = (const float*)d_in[5];
    const float* b2 = (const float*)d_in[6];
    const float* W3 = (const float*)d_in[7];
    const float* b3 = (const float*)d_in[8];
    const float* Wl = (const float*)d_in[9];
    const float* bl = (const float*)d_in[10];
    float* out = (float*)d_out;

    const int N = in_sizes[0] / 128;   // 100000
    const int E = in_sizes[1] / 2;     // 600000
    const int B = out_size;            // 250
    const int Npad = (N + 63) & ~63;   // 100032
    const int npg = N / B;             // 400

    const int* srcp = ei;
    const int* dstp = ei + E;

    char* ws = (char*)d_ws;
    size_t off = 0;
    auto alloc = [&](size_t bytes) -> char* {
        char* p = ws + off;
        off += (bytes + 255) & ~(size_t)255;
        return p;
    };
    float*    bufA    = (float*)   alloc((size_t)Npad * 128 * 4);  // agg out
    float*    bufB    = (float*)   alloc((size_t)Npad * 128 * 4);  // gemm out fp32
    unsigned* hb      = (unsigned*)alloc((size_t)Npad * 64 * 4);   // bf16 copy of h
    float*    dinv    = (float*)   alloc((size_t)N * 4);
    int*      cnt     = (int*)     alloc((size_t)N * 4);
    int*      fill    = (int*)     alloc((size_t)N * 4);
    int*      row_ptr = (int*)     alloc((size_t)N * 4);
    int*      cluster = (int*)     alloc((size_t)N * 4);
    int*      col     = (int*)     alloc((size_t)E * 4);
    int*      bsums   = (int*)     alloc(512 * 4);
    float*    psums   = (float*)   alloc((size_t)B * NPARTS * 3 * 128 * 4);
    int*      pcnts   = (int*)     alloc((size_t)B * NPARTS * 3 * 4);
    (void)ws_size; (void)n_in;

    hipMemsetAsync(cnt,  0, (size_t)N * 4, stream);
    hipMemsetAsync(fill, 0, (size_t)N * 4, stream);

    count_kernel<<<(E + 255) / 256, 256, 0, stream>>>(dstp, cnt, E);
    dinv_kernel<<<(N + 255) / 256, 256, 0, stream>>>(cnt, x, dinv, cluster, N);
    // x -> bf16 for layer-1 gathers (N*128/4 float4 groups)
    f2bf_kernel<<<(N * 32 + 255) / 256, 256, 0, stream>>>(x, hb, N * 32);

    int scanBlocks = (N + 1023) / 1024;
    scan_block<<<scanBlocks, 256, 0, stream>>>(cnt, row_ptr, bsums, N);
    scan_bsums<<<1, 256, 0, stream>>>(bsums, scanBlocks);
    scan_add<<<scanBlocks, 256, 0, stream>>>(row_ptr, bsums, N);

    fill_kernel<<<(E + 255) / 256, 256, 0, stream>>>(srcp, dstp, row_ptr, fill, col, E);

    dim3 gemmGrid(Npad / 64, 2);
    int aggBlocks = (N + 3) / 4;

    // Layer 1: tmp = Agg(xb); h = relu(tmp @ W1 + b1)  (+bf16 copy)
    agg_kernel<<<aggBlocks, 256, 0, stream>>>(hb, bufA, row_ptr, cnt, col, dinv, N);
    gemm128<<<gemmGrid, 256, 0, stream>>>(bufA, W1, b1, bufB, hb, 1);
    // Layer 2
    agg_kernel<<<aggBlocks, 256, 0, stream>>>(hb, bufA, row_ptr, cnt, col, dinv, N);
    gemm128<<<gemmGrid, 256, 0, stream>>>(bufA, W2, b2, bufB, hb, 1);
    // Layer 3 (no relu, no bf16 copy needed)
    agg_kernel<<<aggBlocks, 256, 0, stream>>>(hb, bufA, row_ptr, cnt, col, dinv, N);
    gemm128<<<gemmGrid, 256, 0, stream>>>(bufA, W3, b3, bufB, nullptr, 0);

    pool_part<<<B * NPARTS, 128, 0, stream>>>(bufB, cluster, psums, pcnts, npg);
    head_kernel<<<B, 128, 0, stream>>>(psums, pcnts, Wl, bl, out);
}

// Round 4
// 435.814 us; speedup vs baseline: 1.5776x; 1.5776x over previous
//
#include <hip/hip_runtime.h>
#include <hip/hip_bf16.h>
#include <math.h>

// N=100000 nodes, E=600000 edges, F=H=128, B=250 graphs, 400 nodes/graph.
//
// Pipeline (all h interfaces bf16, fp32 accumulation everywhere):
//   CSR build (histogram -> scan -> fill), dinv, cluster, x->bf16, W->Wt bf16
//   3x { agg: ab = (D^-1/2 (A+I) D^-1/2) hb    (bf16 gathers, bf16 packed out)
//        gemm_mfma: hb = [relu](ab @ W + b)    (16x16x32 bf16 MFMA, bf16 out) }
//   pool_part (16 partials/graph, bf16 reads) + head
//
// R1: pool 113us @5% occupancy -> 16 partials/graph. 671->572us.
// R2: agg gather-byte bound (3x87us, FETCH 177MB) -> bf16 gathers.
// R3: gemm128 regressed to 126us (VGPR 244, occ 10%, fp32 SIMT far from peak).
//     -> MFMA bf16 GEMM + bf16-only h interfaces. Predicted ~15us/gemm.

#define WAVE 64
#define NPARTS 16

typedef __attribute__((ext_vector_type(8))) short bf16x8;
typedef __attribute__((ext_vector_type(4))) float f32x4;

__device__ __forceinline__ float bflo(unsigned u) { return __uint_as_float(u << 16); }
__device__ __forceinline__ float bfhi(unsigned u) { return __uint_as_float(u & 0xffff0000u); }
__device__ __forceinline__ float bfs(unsigned short s) {
    return __uint_as_float(((unsigned)s) << 16);
}
__device__ __forceinline__ unsigned short bf16r(float f) {
    unsigned u = __float_as_uint(f);
    return (unsigned short)((u + 0x7fffu + ((u >> 16) & 1u)) >> 16);
}
__device__ __forceinline__ unsigned pack_bf16(float a, float b) {
    return (unsigned)bf16r(a) | ((unsigned)bf16r(b) << 16);
}

// ---------------- CSR build ----------------

__global__ void count_kernel(const int* __restrict__ dst, int* __restrict__ cnt, int ne) {
    int e = blockIdx.x * blockDim.x + threadIdx.x;
    if (e < ne) atomicAdd(&cnt[dst[e]], 1);
}

__global__ void dinv_kernel(const int* __restrict__ cnt, const float* __restrict__ x,
                            float* __restrict__ dinv, int* __restrict__ cluster, int n) {
    int i = blockIdx.x * blockDim.x + threadIdx.x;
    if (i >= n) return;
    dinv[i] = rsqrtf((float)(cnt[i] + 1));
    float c = x[(size_t)i * 128 + 127] + 2.0f * x[(size_t)i * 128 + 126];
    cluster[i] = (int)(c + 0.5f);
}

// fp32 -> bf16: each thread converts 4 floats -> 2 uints
__global__ void f2bf_kernel(const float* __restrict__ in, unsigned* __restrict__ out,
                            int n4) {
    int i = blockIdx.x * blockDim.x + threadIdx.x;
    if (i >= n4) return;
    float4 v = ((const float4*)in)[i];
    out[i * 2 + 0] = pack_bf16(v.x, v.y);
    out[i * 2 + 1] = pack_bf16(v.z, v.w);
}

// W[k][n] fp32 -> Wt[n][k] bf16, one 128x128 layer per 64 blocks
__global__ void wtrans_kernel(const float* __restrict__ W, unsigned short* __restrict__ Wt) {
    int idx = blockIdx.x * 256 + threadIdx.x;   // 0..16383 per layer handled by grid.y
    const float* Wl = W;                        // caller passes per-layer pointer via grid offset
    int layer = blockIdx.y;
    int n = idx >> 7, k = idx & 127;
    (void)Wl;
    // W pointers are not contiguous across layers; handled host-side by 3 launches.
    Wt[(size_t)layer * 16384 + n * 128 + k] = 0; // overwritten by per-layer launches
}

// simple per-layer transpose+convert
__global__ void wtrans1(const float* __restrict__ W, unsigned short* __restrict__ Wt) {
    int idx = blockIdx.x * 256 + threadIdx.x;   // 0..16383
    int n = idx >> 7, k = idx & 127;
    Wt[n * 128 + k] = bf16r(W[k * 128 + n]);
}

// exclusive scan of cnt -> row_ptr, 1024 elements per block
__global__ void scan_block(const int* __restrict__ in, int* __restrict__ out,
                           int* __restrict__ bsums, int n) {
    __shared__ int lds[256];
    int t = threadIdx.x;
    int base = blockIdx.x * 1024 + t * 4;
    int v0 = (base + 0 < n) ? in[base + 0] : 0;
    int v1 = (base + 1 < n) ? in[base + 1] : 0;
    int v2 = (base + 2 < n) ? in[base + 2] : 0;
    int v3 = (base + 3 < n) ? in[base + 3] : 0;
    int s = v0 + v1 + v2 + v3;
    lds[t] = s;
    __syncthreads();
    for (int off = 1; off < 256; off <<= 1) {
        int add = (t >= off) ? lds[t - off] : 0;
        __syncthreads();
        lds[t] += add;
        __syncthreads();
    }
    int excl = lds[t] - s;
    if (base + 0 < n) out[base + 0] = excl;
    if (base + 1 < n) out[base + 1] = excl + v0;
    if (base + 2 < n) out[base + 2] = excl + v0 + v1;
    if (base + 3 < n) out[base + 3] = excl + v0 + v1 + v2;
    if (t == 255) bsums[blockIdx.x] = lds[255];
}

__global__ void scan_bsums(int* __restrict__ bsums, int nb) {
    __shared__ int lds[256];
    int t = threadIdx.x;
    int v = (t < nb) ? bsums[t] : 0;
    lds[t] = v;
    __syncthreads();
    for (int off = 1; off < 256; off <<= 1) {
        int add = (t >= off) ? lds[t - off] : 0;
        __syncthreads();
        lds[t] += add;
        __syncthreads();
    }
    if (t < nb) bsums[t] = lds[t] - v;   // exclusive
}

__global__ void scan_add(int* __restrict__ out, const int* __restrict__ bsums, int n) {
    int base = blockIdx.x * 1024 + threadIdx.x * 4;
    int add = bsums[blockIdx.x];
#pragma unroll
    for (int i = 0; i < 4; ++i)
        if (base + i < n) out[base + i] += add;
}

__global__ void fill_kernel(const int* __restrict__ src, const int* __restrict__ dst,
                            const int* __restrict__ row_ptr, int* __restrict__ fill,
                            int* __restrict__ col, int ne) {
    int e = blockIdx.x * blockDim.x + threadIdx.x;
    if (e < ne) {
        int d = dst[e];
        int pos = row_ptr[d] + atomicAdd(&fill[d], 1);
        col[pos] = src[e];
    }
}

// ---------------- aggregation: one wave per node, bf16 in/out ----------------

__global__ void agg_kernel(const unsigned* __restrict__ hb, unsigned* __restrict__ outb,
                           const int* __restrict__ row_ptr, const int* __restrict__ cnt,
                           const int* __restrict__ col, const float* __restrict__ dinv,
                           int n) {
    int node = blockIdx.x * (blockDim.x / WAVE) + (threadIdx.x >> 6);
    if (node >= n) return;
    int lane = threadIdx.x & 63;
    float di = dinv[node];
    unsigned self = hb[(size_t)node * 64 + lane];
    float w0 = di * di;
    float ax = bflo(self) * w0;
    float ay = bfhi(self) * w0;
    int s0 = row_ptr[node];
    int d  = cnt[node];
    int i = 0;
    for (; i + 1 < d; i += 2) {
        int sa = col[s0 + i];
        int sb = col[s0 + i + 1];
        float wa = di * dinv[sa];
        float wb = di * dinv[sb];
        unsigned ua = hb[(size_t)sa * 64 + lane];
        unsigned ub = hb[(size_t)sb * 64 + lane];
        ax += wa * bflo(ua) + wb * bflo(ub);
        ay += wa * bfhi(ua) + wb * bfhi(ub);
    }
    if (i < d) {
        int s = col[s0 + i];
        float w = di * dinv[s];
        unsigned u = hb[(size_t)s * 64 + lane];
        ax += w * bflo(u);
        ay += w * bfhi(u);
    }
    outb[(size_t)node * 64 + lane] = pack_bf16(ax, ay);
}

// ---------------- MFMA bf16 GEMM: Cb[M][128] = [relu](A[M][128] @ W + b) -------------
// A row-major bf16 (ushort). Wt[n][k] bf16 (pre-transposed; 32KB, L1-resident).
// Block = 4 waves; wave computes 32 rows x 128 cols via 2x8 tiles of 16x16x32.
// Fragment layouts (verified, learn_hip m89/m91/m120):
//   A-frag: lane holds A[m=lane&15][k=quad*8+j]  -> 8 contiguous bf16 along k
//   B-frag: lane holds B[k=quad*8+j][n=lane&15]  -> 8 contiguous in Wt[n][k]
//   C/D:    reg i -> row=quad*4+i, col=lane&15

__global__ __launch_bounds__(256) void gemm_mfma(const unsigned short* __restrict__ A,
                                                 const unsigned short* __restrict__ Wt,
                                                 const float* __restrict__ bias,
                                                 unsigned short* __restrict__ Cb,
                                                 int relu) {
    __shared__ unsigned short sOut[4][32 * 128];   // 32 KB: per-wave staging
    const int t = threadIdx.x;
    const int wave = t >> 6, lane = t & 63;
    const int quad = lane >> 4, lr = lane & 15;
    const size_t row0 = (size_t)blockIdx.x * 128 + wave * 32;

    f32x4 acc[2][8];
#pragma unroll
    for (int i2 = 0; i2 < 2; ++i2)
#pragma unroll
        for (int ct = 0; ct < 8; ++ct) acc[i2][ct] = (f32x4){0.f, 0.f, 0.f, 0.f};

    const unsigned short* arow0 = A + (row0 + lr) * 128;
    const unsigned short* arow1 = arow0 + 16 * 128;
#pragma unroll
    for (int kc = 0; kc < 4; ++kc) {
        int kb = kc * 32 + quad * 8;
        bf16x8 a0 = *(const bf16x8*)(arow0 + kb);
        bf16x8 a1 = *(const bf16x8*)(arow1 + kb);
#pragma unroll
        for (int ct = 0; ct < 8; ++ct) {
            bf16x8 b = *(const bf16x8*)(Wt + (ct * 16 + lr) * 128 + kb);
            acc[0][ct] = __builtin_amdgcn_mfma_f32_16x16x32_bf16(a0, b, acc[0][ct], 0, 0, 0);
            acc[1][ct] = __builtin_amdgcn_mfma_f32_16x16x32_bf16(a1, b, acc[1][ct], 0, 0, 0);
        }
    }

    // epilogue: bias (+relu), pack bf16 into LDS, then coalesced stream-out
#pragma unroll
    for (int ct = 0; ct < 8; ++ct) {
        float bs = bias[ct * 16 + lr];
#pragma unroll
        for (int i2 = 0; i2 < 2; ++i2)
#pragma unroll
            for (int i = 0; i < 4; ++i) {
                float v = acc[i2][ct][i] + bs;
                if (relu) v = fmaxf(v, 0.f);
                int rl = i2 * 16 + quad * 4 + i;
                sOut[wave][rl * 128 + ct * 16 + lr] = bf16r(v);
            }
    }
    __syncthreads();
    const uint4* srcv = (const uint4*)sOut[wave];
    uint4* dstv = (uint4*)(Cb + row0 * 128);
#pragma unroll
    for (int it = 0; it < 8; ++it)
        dstv[it * 64 + lane] = srcv[it * 64 + lane];
}

// ---------------- pooling: 16 partial blocks per graph, bf16 reads ----------------

__global__ void pool_part(const unsigned short* __restrict__ h,
                          const int* __restrict__ cluster,
                          float* __restrict__ part_sums, int* __restrict__ part_cnts,
                          int npg) {
    int blk = blockIdx.x;
    int g = blk / NPARTS, p = blk % NPARTS;
    int j = threadIdx.x;
    int per = npg / NPARTS;
    int base = g * npg + p * per;
    float a0 = 0.f, a1 = 0.f, a2 = 0.f;
    int n0 = 0, n1 = 0, n2 = 0;
    for (int i = 0; i < per; ++i) {
        int node = base + i;
        float v = bfs(h[(size_t)node * 128 + j]);
        int c = cluster[node];
        if (c == 0)      { a0 += v; n0++; }
        else if (c == 1) { a1 += v; n1++; }
        else             { a2 += v; n2++; }
    }
    size_t o = (size_t)blk * 3 * 128 + j;
    part_sums[o]       = a0;
    part_sums[o + 128] = a1;
    part_sums[o + 256] = a2;
    if (j == 0) {
        part_cnts[blk * 3 + 0] = n0;
        part_cnts[blk * 3 + 1] = n1;
        part_cnts[blk * 3 + 2] = n2;
    }
}

__global__ void head_kernel(const float* __restrict__ part_sums,
                            const int* __restrict__ part_cnts,
                            const float* __restrict__ Wl, const float* __restrict__ bl,
                            float* __restrict__ out) {
    int b = blockIdx.x, t = threadIdx.x;
    float s0 = 0.f, s1 = 0.f, s2 = 0.f;
    int n0 = 0, n1 = 0, n2 = 0;
#pragma unroll
    for (int p = 0; p < NPARTS; ++p) {
        int blk = b * NPARTS + p;
        size_t o = (size_t)blk * 3 * 128 + t;
        s0 += part_sums[o];
        s1 += part_sums[o + 128];
        s2 += part_sums[o + 256];
        n0 += part_cnts[blk * 3 + 0];
        n1 += part_cnts[blk * 3 + 1];
        n2 += part_cnts[blk * 3 + 2];
    }
    float z = s0 * (1.0f / fmaxf((float)n0, 1.0f)) * Wl[t]
            + s1 * (1.0f / fmaxf((float)n1, 1.0f)) * Wl[128 + t]
            + s2 * (1.0f / fmaxf((float)n2, 1.0f)) * Wl[256 + t];
    for (int off = 32; off > 0; off >>= 1) z += __shfl_down(z, off);
    __shared__ float partial[2];
    if ((t & 63) == 0) partial[t >> 6] = z;
    __syncthreads();
    if (t == 0) {
        float zz = partial[0] + partial[1] + bl[0];
        out[b] = 1.0f / (1.0f + expf(-zz));
    }
}

// ---------------- host ----------------

extern "C" void kernel_launch(void* const* d_in, const int* in_sizes, int n_in,
                              void* d_out, int out_size, void* d_ws, size_t ws_size,
                              hipStream_t stream) {
    const float* x  = (const float*)d_in[0];
    const int*   ei = (const int*)d_in[1];
    const float* W1 = (const float*)d_in[3];
    const float* b1 = (const float*)d_in[4];
    const float* W2 = (const float*)d_in[5];
    const float* b2 = (const float*)d_in[6];
    const float* W3 = (const float*)d_in[7];
    const float* b3 = (const float*)d_in[8];
    const float* Wl = (const float*)d_in[9];
    const float* bl = (const float*)d_in[10];
    float* out = (float*)d_out;

    const int N = in_sizes[0] / 128;        // 100000
    const int E = in_sizes[1] / 2;          // 600000
    const int B = out_size;                 // 250
    const int Npad = (N + 127) & ~127;      // 100096 (gemm tiles of 128 rows)
    const int npg = N / B;                  // 400

    const int* srcp = ei;
    const int* dstp = ei + E;

    char* ws = (char*)d_ws;
    size_t off = 0;
    auto alloc = [&](size_t bytes) -> char* {
        char* p = ws + off;
        off += (bytes + 255) & ~(size_t)255;
        return p;
    };
    unsigned short* hb  = (unsigned short*)alloc((size_t)Npad * 128 * 2); // bf16 h
    unsigned short* ab  = (unsigned short*)alloc((size_t)Npad * 128 * 2); // bf16 agg out
    unsigned short* wt  = (unsigned short*)alloc((size_t)3 * 16384 * 2);  // Wt bf16 x3
    float* dinv    = (float*)alloc((size_t)N * 4);
    int*   cnt     = (int*)  alloc((size_t)N * 4);
    int*   fill    = (int*)  alloc((size_t)N * 4);
    int*   row_ptr = (int*)  alloc((size_t)N * 4);
    int*   cluster = (int*)  alloc((size_t)N * 4);
    int*   col     = (int*)  alloc((size_t)E * 4);
    int*   bsums   = (int*)  alloc(512 * 4);
    float* psums   = (float*)alloc((size_t)B * NPARTS * 3 * 128 * 4);
    int*   pcnts   = (int*)  alloc((size_t)B * NPARTS * 3 * 4);
    (void)ws_size; (void)n_in;

    hipMemsetAsync(cnt,  0, (size_t)N * 4, stream);
    hipMemsetAsync(fill, 0, (size_t)N * 4, stream);

    count_kernel<<<(E + 255) / 256, 256, 0, stream>>>(dstp, cnt, E);
    dinv_kernel<<<(N + 255) / 256, 256, 0, stream>>>(cnt, x, dinv, cluster, N);
    f2bf_kernel<<<(N * 32 + 255) / 256, 256, 0, stream>>>(x, (unsigned*)hb, N * 32);
    wtrans1<<<64, 256, 0, stream>>>(W1, wt);
    wtrans1<<<64, 256, 0, stream>>>(W2, wt + 16384);
    wtrans1<<<64, 256, 0, stream>>>(W3, wt + 32768);

    int scanBlocks = (N + 1023) / 1024;
    scan_block<<<scanBlocks, 256, 0, stream>>>(cnt, row_ptr, bsums, N);
    scan_bsums<<<1, 256, 0, stream>>>(bsums, scanBlocks);
    scan_add<<<scanBlocks, 256, 0, stream>>>(row_ptr, bsums, N);

    fill_kernel<<<(E + 255) / 256, 256, 0, stream>>>(srcp, dstp, row_ptr, fill, col, E);

    int gemmBlocks = Npad / 128;            // 782
    int aggBlocks = (N + 3) / 4;

    agg_kernel<<<aggBlocks, 256, 0, stream>>>((unsigned*)hb, (unsigned*)ab,
                                              row_ptr, cnt, col, dinv, N);
    gemm_mfma<<<gemmBlocks, 256, 0, stream>>>(ab, wt, b1, hb, 1);
    agg_kernel<<<aggBlocks, 256, 0, stream>>>((unsigned*)hb, (unsigned*)ab,
                                              row_ptr, cnt, col, dinv, N);
    gemm_mfma<<<gemmBlocks, 256, 0, stream>>>(ab, wt + 16384, b2, hb, 1);
    agg_kernel<<<aggBlocks, 256, 0, stream>>>((unsigned*)hb, (unsigned*)ab,
                                              row_ptr, cnt, col, dinv, N);
    gemm_mfma<<<gemmBlocks, 256, 0, stream>>>(ab, wt + 32768, b3, hb, 0);

    pool_part<<<B * NPARTS, 128, 0, stream>>>(hb, cluster, psums, pcnts, npg);
    head_kernel<<<B, 128, 0, stream>>>(psums, pcnts, Wl, bl, out);
}

// Round 5
// 353.822 us; speedup vs baseline: 1.9432x; 1.2317x over previous
//
#include <hip/hip_runtime.h>
#include <hip/hip_bf16.h>
#include <math.h>

// N=100000 nodes, E=600000 edges, F=H=128, B=250 graphs, 400 nodes/graph.
//
// Pipeline (all h interfaces bf16, fp32 accumulation):
//   count -> prep (x->bf16 + dinv + cluster) -> scan -> fill (CSR with (col,w) int2)
//   3x { agg: ab = (D^-1/2 (A+I) D^-1/2) hb    (4 nodes/wave, 16B/lane gathers)
//        gemm_mfma: hb = [relu](ab @ W + b)    (LDS-staged Wt, 16x16x32 MFMA) }
//   pool_part (16 partials/graph, bf16 reads) + head
//
// R1: pool 113us @5% occ -> 16 partials/graph. 671->572.
// R2: agg gather-byte bound -> bf16 gathers. (gemm regressed)
// R3: fp32 SIMT gemm 126us -> MFMA bf16, bf16-only h. 688->436.
// R4: agg latency-bound (2.25TB/s, VALU 27%) -> 4 nodes/wave + precomputed edge
//     weights + pipelined (col,w). gemm L1-thrash on Wt -> LDS-staged B.

#define WAVE 64
#define NPARTS 16
#define WPAD 136   // padded LDS row stride (ushorts) for conflict-free ds_read_b128

typedef __attribute__((ext_vector_type(8))) short bf16x8;
typedef __attribute__((ext_vector_type(4))) float f32x4;

__device__ __forceinline__ float bflo(unsigned u) { return __uint_as_float(u << 16); }
__device__ __forceinline__ float bfhi(unsigned u) { return __uint_as_float(u & 0xffff0000u); }
__device__ __forceinline__ float bfs(unsigned short s) {
    return __uint_as_float(((unsigned)s) << 16);
}
__device__ __forceinline__ unsigned short bf16r(float f) {
    unsigned u = __float_as_uint(f);
    return (unsigned short)((u + 0x7fffu + ((u >> 16) & 1u)) >> 16);
}
__device__ __forceinline__ unsigned pack_bf16(float a, float b) {
    return (unsigned)bf16r(a) | ((unsigned)bf16r(b) << 16);
}
__device__ __forceinline__ void fma8(float* acc, float w, uint4 u) {
    acc[0] += w * bflo(u.x); acc[1] += w * bfhi(u.x);
    acc[2] += w * bflo(u.y); acc[3] += w * bfhi(u.y);
    acc[4] += w * bflo(u.z); acc[5] += w * bfhi(u.z);
    acc[6] += w * bflo(u.w); acc[7] += w * bfhi(u.w);
}

// ---------------- CSR build ----------------

__global__ void count_kernel(const int* __restrict__ dst, int* __restrict__ cnt, int ne) {
    int e = blockIdx.x * blockDim.x + threadIdx.x;
    if (e < ne) atomicAdd(&cnt[dst[e]], 1);
}

// fused: x -> bf16, plus per-row dinv and cluster (one pass over x)
__global__ void prep_kernel(const float* __restrict__ x, unsigned* __restrict__ hb,
                            const int* __restrict__ cnt, float* __restrict__ dinv,
                            int* __restrict__ cluster, int n32) {
    int i = blockIdx.x * blockDim.x + threadIdx.x;   // handles 4 floats
    if (i >= n32) return;
    float4 v = ((const float4*)x)[i];
    hb[i * 2 + 0] = pack_bf16(v.x, v.y);
    hb[i * 2 + 1] = pack_bf16(v.z, v.w);
    if ((i & 31) == 31) {                            // floats 124..127 of this row
        int row = i >> 5;
        dinv[row] = rsqrtf((float)(cnt[row] + 1));
        cluster[row] = (int)(v.w + 2.0f * v.z + 0.5f);
    }
}

// exclusive scan of cnt -> row_ptr, 1024 elements per block
__global__ void scan_block(const int* __restrict__ in, int* __restrict__ out,
                           int* __restrict__ bsums, int n) {
    __shared__ int lds[256];
    int t = threadIdx.x;
    int base = blockIdx.x * 1024 + t * 4;
    int v0 = (base + 0 < n) ? in[base + 0] : 0;
    int v1 = (base + 1 < n) ? in[base + 1] : 0;
    int v2 = (base + 2 < n) ? in[base + 2] : 0;
    int v3 = (base + 3 < n) ? in[base + 3] : 0;
    int s = v0 + v1 + v2 + v3;
    lds[t] = s;
    __syncthreads();
    for (int off = 1; off < 256; off <<= 1) {
        int add = (t >= off) ? lds[t - off] : 0;
        __syncthreads();
        lds[t] += add;
        __syncthreads();
    }
    int excl = lds[t] - s;
    if (base + 0 < n) out[base + 0] = excl;
    if (base + 1 < n) out[base + 1] = excl + v0;
    if (base + 2 < n) out[base + 2] = excl + v0 + v1;
    if (base + 3 < n) out[base + 3] = excl + v0 + v1 + v2;
    if (t == 255) bsums[blockIdx.x] = lds[255];
}

__global__ void scan_bsums(int* __restrict__ bsums, int nb) {
    __shared__ int lds[256];
    int t = threadIdx.x;
    int v = (t < nb) ? bsums[t] : 0;
    lds[t] = v;
    __syncthreads();
    for (int off = 1; off < 256; off <<= 1) {
        int add = (t >= off) ? lds[t - off] : 0;
        __syncthreads();
        lds[t] += add;
        __syncthreads();
    }
    if (t < nb) bsums[t] = lds[t] - v;   // exclusive
}

__global__ void scan_add(int* __restrict__ out, const int* __restrict__ bsums, int n) {
    int base = blockIdx.x * 1024 + threadIdx.x * 4;
    int add = bsums[blockIdx.x];
#pragma unroll
    for (int i = 0; i < 4; ++i)
        if (base + i < n) out[base + i] += add;
}

// CSR fill with precomputed edge weight: ce[pos] = (src, dinv[src]*dinv[dst])
__global__ void fill_kernel(const int* __restrict__ src, const int* __restrict__ dst,
                            const int* __restrict__ row_ptr, int* __restrict__ fill,
                            int2* __restrict__ ce, const float* __restrict__ dinv,
                            int ne) {
    int e = blockIdx.x * blockDim.x + threadIdx.x;
    if (e < ne) {
        int d = dst[e], s = src[e];
        int pos = row_ptr[d] + atomicAdd(&fill[d], 1);
        ce[pos] = make_int2(s, __float_as_int(dinv[s] * dinv[d]));
    }
}

// ---------------- aggregation: 4 nodes per wave, 16 lanes x 16B per row ----------
// out[n][:] = dinv[n]^2 * hb[n][:] + sum_{(s,w) in CSR(n)} w * hb[s][:]

__global__ void agg_kernel(const uint4* __restrict__ hb4, uint4* __restrict__ out4,
                           const int* __restrict__ row_ptr, const int* __restrict__ cnt,
                           const int2* __restrict__ ce, const float* __restrict__ dinv,
                           int n) {
    int wid = blockIdx.x * (blockDim.x >> 6) + (threadIdx.x >> 6);
    int lane = threadIdx.x & 63;
    int g = lane >> 4, sl = lane & 15;     // group (node) and sublane (feature chunk)
    int node = wid * 4 + g;
    bool ok = node < n;
    int nc = ok ? node : (n - 1);
    float di = dinv[nc];
    uint4 self = hb4[(size_t)nc * 16 + sl];
    float w0 = di * di;
    float acc[8];
    acc[0] = w0 * bflo(self.x); acc[1] = w0 * bfhi(self.x);
    acc[2] = w0 * bflo(self.y); acc[3] = w0 * bfhi(self.y);
    acc[4] = w0 * bflo(self.z); acc[5] = w0 * bfhi(self.z);
    acc[6] = w0 * bflo(self.w); acc[7] = w0 * bfhi(self.w);
    int s0 = row_ptr[nc];
    int deg = ok ? cnt[nc] : 0;
    int2 cw = (deg > 0) ? ce[s0] : make_int2(0, 0);
    for (int i = 0; i < deg; ++i) {
        int2 nxt = (i + 1 < deg) ? ce[s0 + i + 1] : cw;   // pipelined prefetch
        float w = __int_as_float(cw.y);
        uint4 u = hb4[(size_t)cw.x * 16 + sl];
        fma8(acc, w, u);
        cw = nxt;
    }
    if (ok) {
        uint4 o;
        o.x = pack_bf16(acc[0], acc[1]);
        o.y = pack_bf16(acc[2], acc[3]);
        o.z = pack_bf16(acc[4], acc[5]);
        o.w = pack_bf16(acc[6], acc[7]);
        out4[(size_t)node * 16 + sl] = o;
    }
}

// ---------------- MFMA bf16 GEMM: Cb[M][128] = [relu](A[M][128] @ W + b) -------------
// Wt[n][k] bf16, staged once per block into LDS (padded stride WPAD).
// Block = 4 waves; wave computes 32 rows x 128 cols via 2x8 tiles of 16x16x32.
// Fragment layouts (verified):
//   A-frag: lane holds A[m=lane&15][k=quad*8+j]
//   B-frag: lane holds B[k=quad*8+j][n=lane&15] = Wt[n][k] contiguous in k
//   C/D:    reg i -> row=quad*4+i, col=lane&15

__global__ __launch_bounds__(256) void gemm_mfma(const unsigned short* __restrict__ A,
                                                 const unsigned short* __restrict__ Wt,
                                                 const float* __restrict__ bias,
                                                 unsigned short* __restrict__ Cb,
                                                 int relu) {
    __shared__ unsigned short sm[128 * WPAD];   // 34816 B; reused as epilogue staging
    const int t = threadIdx.x;
    const int wave = t >> 6, lane = t & 63;
    const int quad = lane >> 4, lr = lane & 15;
    const size_t row0 = (size_t)blockIdx.x * 128 + wave * 32;

    // stage Wt -> sm with padding: thread t copies 64 ushorts (row t>>1, half t&1)
    {
        int r = t >> 1, h = t & 1;
        const uint4* s = (const uint4*)(Wt + r * 128 + h * 64);
        uint4* d = (uint4*)(sm + r * WPAD + h * 64);
#pragma unroll
        for (int i = 0; i < 8; ++i) d[i] = s[i];
    }
    __syncthreads();

    f32x4 acc[2][8];
#pragma unroll
    for (int i2 = 0; i2 < 2; ++i2)
#pragma unroll
        for (int ct = 0; ct < 8; ++ct) acc[i2][ct] = (f32x4){0.f, 0.f, 0.f, 0.f};

    const unsigned short* arow0 = A + (row0 + lr) * 128;
    const unsigned short* arow1 = arow0 + 16 * 128;
#pragma unroll
    for (int kc = 0; kc < 4; ++kc) {
        int kb = kc * 32 + quad * 8;
        bf16x8 a0 = *(const bf16x8*)(arow0 + kb);
        bf16x8 a1 = *(const bf16x8*)(arow1 + kb);
#pragma unroll
        for (int ct = 0; ct < 8; ++ct) {
            bf16x8 b = *(const bf16x8*)(sm + (ct * 16 + lr) * WPAD + kb);
            acc[0][ct] = __builtin_amdgcn_mfma_f32_16x16x32_bf16(a0, b, acc[0][ct], 0, 0, 0);
            acc[1][ct] = __builtin_amdgcn_mfma_f32_16x16x32_bf16(a1, b, acc[1][ct], 0, 0, 0);
        }
    }
    __syncthreads();   // all waves done reading sm -> reuse as output staging

    unsigned short* sOut = sm + wave * 4096;   // 32 rows x 128 cols per wave
#pragma unroll
    for (int ct = 0; ct < 8; ++ct) {
        float bs = bias[ct * 16 + lr];
#pragma unroll
        for (int i2 = 0; i2 < 2; ++i2)
#pragma unroll
            for (int i = 0; i < 4; ++i) {
                float v = acc[i2][ct][i] + bs;
                if (relu) v = fmaxf(v, 0.f);
                sOut[(i2 * 16 + quad * 4 + i) * 128 + ct * 16 + lr] = bf16r(v);
            }
    }
    __syncthreads();
    const uint4* srcv = (const uint4*)sOut;
    uint4* dstv = (uint4*)(Cb + row0 * 128);
#pragma unroll
    for (int it = 0; it < 8; ++it)
        dstv[it * 64 + lane] = srcv[it * 64 + lane];
}

// simple per-layer transpose+convert: W[k][n] fp32 -> Wt[n][k] bf16
__global__ void wtrans1(const float* __restrict__ W, unsigned short* __restrict__ Wt) {
    int idx = blockIdx.x * 256 + threadIdx.x;   // 0..16383
    int n = idx >> 7, k = idx & 127;
    Wt[n * 128 + k] = bf16r(W[k * 128 + n]);
}

// ---------------- pooling: 16 partial blocks per graph, bf16 reads ----------------

__global__ void pool_part(const unsigned short* __restrict__ h,
                          const int* __restrict__ cluster,
                          float* __restrict__ part_sums, int* __restrict__ part_cnts,
                          int npg) {
    int blk = blockIdx.x;
    int g = blk / NPARTS, p = blk % NPARTS;
    int j = threadIdx.x;
    int per = npg / NPARTS;
    int base = g * npg + p * per;
    float a0 = 0.f, a1 = 0.f, a2 = 0.f;
    int n0 = 0, n1 = 0, n2 = 0;
    for (int i = 0; i < per; ++i) {
        int node = base + i;
        float v = bfs(h[(size_t)node * 128 + j]);
        int c = cluster[node];
        if (c == 0)      { a0 += v; n0++; }
        else if (c == 1) { a1 += v; n1++; }
        else             { a2 += v; n2++; }
    }
    size_t o = (size_t)blk * 3 * 128 + j;
    part_sums[o]       = a0;
    part_sums[o + 128] = a1;
    part_sums[o + 256] = a2;
    if (j == 0) {
        part_cnts[blk * 3 + 0] = n0;
        part_cnts[blk * 3 + 1] = n1;
        part_cnts[blk * 3 + 2] = n2;
    }
}

__global__ void head_kernel(const float* __restrict__ part_sums,
                            const int* __restrict__ part_cnts,
                            const float* __restrict__ Wl, const float* __restrict__ bl,
                            float* __restrict__ out) {
    int b = blockIdx.x, t = threadIdx.x;
    float s0 = 0.f, s1 = 0.f, s2 = 0.f;
    int n0 = 0, n1 = 0, n2 = 0;
#pragma unroll
    for (int p = 0; p < NPARTS; ++p) {
        int blk = b * NPARTS + p;
        size_t o = (size_t)blk * 3 * 128 + t;
        s0 += part_sums[o];
        s1 += part_sums[o + 128];
        s2 += part_sums[o + 256];
        n0 += part_cnts[blk * 3 + 0];
        n1 += part_cnts[blk * 3 + 1];
        n2 += part_cnts[blk * 3 + 2];
    }
    float z = s0 * (1.0f / fmaxf((float)n0, 1.0f)) * Wl[t]
            + s1 * (1.0f / fmaxf((float)n1, 1.0f)) * Wl[128 + t]
            + s2 * (1.0f / fmaxf((float)n2, 1.0f)) * Wl[256 + t];
    for (int off = 32; off > 0; off >>= 1) z += __shfl_down(z, off);
    __shared__ float partial[2];
    if ((t & 63) == 0) partial[t >> 6] = z;
    __syncthreads();
    if (t == 0) {
        float zz = partial[0] + partial[1] + bl[0];
        out[b] = 1.0f / (1.0f + expf(-zz));
    }
}

// ---------------- host ----------------

extern "C" void kernel_launch(void* const* d_in, const int* in_sizes, int n_in,
                              void* d_out, int out_size, void* d_ws, size_t ws_size,
                              hipStream_t stream) {
    const float* x  = (const float*)d_in[0];
    const int*   ei = (const int*)d_in[1];
    const float* W1 = (const float*)d_in[3];
    const float* b1 = (const float*)d_in[4];
    const float* W2 = (const float*)d_in[5];
    const float* b2 = (const float*)d_in[6];
    const float* W3 = (const float*)d_in[7];
    const float* b3 = (const float*)d_in[8];
    const float* Wl = (const float*)d_in[9];
    const float* bl = (const float*)d_in[10];
    float* out = (float*)d_out;

    const int N = in_sizes[0] / 128;        // 100000
    const int E = in_sizes[1] / 2;          // 600000
    const int B = out_size;                 // 250
    const int Npad = (N + 127) & ~127;      // 100096
    const int npg = N / B;                  // 400

    const int* srcp = ei;
    const int* dstp = ei + E;

    char* ws = (char*)d_ws;
    size_t off = 0;
    auto alloc = [&](size_t bytes) -> char* {
        char* p = ws + off;
        off += (bytes + 255) & ~(size_t)255;
        return p;
    };
    unsigned short* hb  = (unsigned short*)alloc((size_t)Npad * 128 * 2); // bf16 h
    unsigned short* ab  = (unsigned short*)alloc((size_t)Npad * 128 * 2); // bf16 agg out
    unsigned short* wt  = (unsigned short*)alloc((size_t)3 * 16384 * 2);  // Wt bf16 x3
    float* dinv    = (float*)alloc((size_t)N * 4);
    int*   cnt     = (int*)  alloc((size_t)N * 4);
    int*   fill    = (int*)  alloc((size_t)N * 4);
    int*   row_ptr = (int*)  alloc((size_t)N * 4);
    int*   cluster = (int*)  alloc((size_t)N * 4);
    int2*  ce      = (int2*) alloc((size_t)E * 8);
    int*   bsums   = (int*)  alloc(512 * 4);
    float* psums   = (float*)alloc((size_t)B * NPARTS * 3 * 128 * 4);
    int*   pcnts   = (int*)  alloc((size_t)B * NPARTS * 3 * 4);
    (void)ws_size; (void)n_in;

    hipMemsetAsync(cnt,  0, (size_t)N * 4, stream);
    hipMemsetAsync(fill, 0, (size_t)N * 4, stream);

    count_kernel<<<(E + 255) / 256, 256, 0, stream>>>(dstp, cnt, E);
    prep_kernel<<<(N * 32 + 255) / 256, 256, 0, stream>>>(x, (unsigned*)hb, cnt,
                                                          dinv, cluster, N * 32);
    wtrans1<<<64, 256, 0, stream>>>(W1, wt);
    wtrans1<<<64, 256, 0, stream>>>(W2, wt + 16384);
    wtrans1<<<64, 256, 0, stream>>>(W3, wt + 32768);

    int scanBlocks = (N + 1023) / 1024;
    scan_block<<<scanBlocks, 256, 0, stream>>>(cnt, row_ptr, bsums, N);
    scan_bsums<<<1, 256, 0, stream>>>(bsums, scanBlocks);
    scan_add<<<scanBlocks, 256, 0, stream>>>(row_ptr, bsums, N);

    fill_kernel<<<(E + 255) / 256, 256, 0, stream>>>(srcp, dstp, row_ptr, fill,
                                                     ce, dinv, E);

    int gemmBlocks = Npad / 128;            // 782
    int aggBlocks = (N + 15) / 16;          // 6250 (4 waves x 4 nodes per block)

    agg_kernel<<<aggBlocks, 256, 0, stream>>>((const uint4*)hb, (uint4*)ab,
                                              row_ptr, cnt, ce, dinv, N);
    gemm_mfma<<<gemmBlocks, 256, 0, stream>>>(ab, wt, b1, hb, 1);
    agg_kernel<<<aggBlocks, 256, 0, stream>>>((const uint4*)hb, (uint4*)ab,
                                              row_ptr, cnt, ce, dinv, N);
    gemm_mfma<<<gemmBlocks, 256, 0, stream>>>(ab, wt + 16384, b2, hb, 1);
    agg_kernel<<<aggBlocks, 256, 0, stream>>>((const uint4*)hb, (uint4*)ab,
                                              row_ptr, cnt, ce, dinv, N);
    gemm_mfma<<<gemmBlocks, 256, 0, stream>>>(ab, wt + 32768, b3, hb, 0);

    pool_part<<<B * NPARTS, 128, 0, stream>>>(hb, cluster, psums, pcnts, npg);
    head_kernel<<<B, 128, 0, stream>>>(psums, pcnts, Wl, bl, out);
}